// Round 8
// baseline (432.110 us; speedup 1.0000x reference)
//
#include <hip/hip_runtime.h>
#include <math.h>

#define NB 16
#define NN 24
#define FF 128
#define CC 27
#define MAXNBR 32     /* physically <= 23 possible (image spacing L > 2r) */
#define NCAND (NN*CC) /* 648 candidates per atom */

__device__ __forceinline__ float softplusf(float x){ return fmaxf(x,0.f) + log1pf(expf(-fabsf(x))); }
__device__ __forceinline__ float sigmoidf(float x){ return 1.f/(1.f+expf(-x)); }

// One block per batch. 1024 threads = 16 waves.
//   waves 0-7 : phase A (feat0 + neighbor list)      } concurrent, joined at B2
//   waves 8-10: wave-synchronous sigma (one FC layer each, shuffle-only)
// then all 16 waves: 3 conv layers (proj + edges) entirely in LDS, then mean+FC+head.
__global__ void __launch_bounds__(1024)
k_fused(const float* __restrict__ pos,  const float* __restrict__ cell,
        const float* __restrict__ emb,
        const float* __restrict__ conv_Wf, const float* __restrict__ conv_bf,
        const float* __restrict__ conv_Ws, const float* __restrict__ conv_bs,
        const float* __restrict__ fc_W,  const float* __restrict__ fc_b,
        const float* __restrict__ W_out, const float* __restrict__ b_out,
        const int* __restrict__ z,       float* __restrict__ out)
{
  const int b   = blockIdx.x;
  const int tid = threadIdx.x;
  const int g   = tid >> 7;       // group 0..7 (128 lanes each)
  const int f   = tid & 127;      // feature lane
  const int wv  = tid >> 6;       // wave 0..15
  const int lane= tid & 63;

  __shared__ __align__(16) float s_ftT[FF*28];    // transposed feat [k][atom], pad 28
  __shared__ float s_ft  [NN*FF];                 // feat [atom][f]
  __shared__ float s_proj[NN*4*FF];               // [atom][gi,gj,si,sj][f]
  __shared__ int   s_nj[NN*MAXNBR];
  __shared__ float s_nd[NN*MAXNBR];
  __shared__ float s_nw[NN*MAXNBR];
  __shared__ int   s_cnt[NN];
  __shared__ float s_cell[9];
  __shared__ float s_pos[NN*3];
  __shared__ float s_sigma[3];
  __shared__ float s_hh[FF], s_tmp[FF], s_red[FF];
  __shared__ float s_part[8][FF];

  // ---- preload tiny inputs ----
  if (tid < 9)  s_cell[tid] = cell[b*9+tid];
  if (tid < NN*3) s_pos[tid] = pos[b*NN*3 + tid];
  if (tid < NN) s_cnt[tid] = 0;
  __syncthreads();                                 // B1

  if (wv < 8) {
    // ================= phase A: feat0 + radius + neighbor list =================
    const float* c = s_cell;
    float cx = c[4]*c[8] - c[5]*c[7];
    float cy = c[5]*c[6] - c[3]*c[8];
    float cz = c[3]*c[7] - c[4]*c[6];
    float vol = c[0]*cx + c[1]*cy + c[2]*cz;
    const float rb  = cbrtf(fabsf(vol)/(float)NN); // RADIUS_RATE = 1
    const float rb2 = rb*rb;
    for (int idx = tid; idx < NN*FF; idx += 512) {
      int a = idx >> 7, ff = idx & 127;
      int zi = z[b*NN+a]; if (zi < 1) zi = 1; if (zi > 100) zi = 100;
      float v = tanhf(emb[(zi-1)*FF+ff]);
      s_ft[a*FF+ff] = v;
      s_ftT[ff*28+a] = v;
    }
    const float PI = 3.14159265358979323846f;
    for (int cand = tid; cand < NN*NCAND; cand += 512) {
      int a = cand / NCAND;
      int r = cand - a*NCAND;
      int j = r / CC, cc = r - j*CC;
      float gx = (float)(cc/9) - 1.0f;
      float gy = (float)((cc/3)%3) - 1.0f;
      float gz = (float)(cc%3) - 1.0f;
      float ox = gx*s_cell[0] + gy*s_cell[3] + gz*s_cell[6];
      float oy = gx*s_cell[1] + gy*s_cell[4] + gz*s_cell[7];
      float oz = gx*s_cell[2] + gy*s_cell[5] + gz*s_cell[8];
      float dx = s_pos[a*3+0] - (s_pos[j*3+0] + ox);
      float dy = s_pos[a*3+1] - (s_pos[j*3+1] + oy);
      float dz = s_pos[a*3+2] - (s_pos[j*3+2] + oz);
      float d2 = dx*dx + dy*dy + dz*dz;
      if (d2 <= rb2 && d2 > 1e-4f) {
        float dist = sqrtf(fmaxf(d2, 1e-12f));
        float w = cosf(dist*PI/rb) + 1.0f;
        int slot = atomicAdd(&s_cnt[a], 1);        // LDS atomic
        if (slot < MAXNBR) {
          s_nj[a*MAXNBR+slot] = j;
          s_nd[a*MAXNBR+slot] = dist;
          s_nw[a*MAXNBR+slot] = w;
        }
      }
    }
  } else if (wv < 11) {
    // ================= sigma: wave-synchronous power iteration =================
    // u,v: 128 floats as 2 regs/lane (elem lane, lane+64); norms via shuffle butterfly.
    const int l = wv - 8;
    const float* W = fc_W + l*FF*FF;
    const float4* r0 = (const float4*)(W + lane*FF);        // row lane
    const float4* r1 = (const float4*)(W + (lane+64)*FF);   // row lane+64
    float u0 = 0.08838834764831845f, u1 = u0;               // ones/||ones|| = 1/sqrt(128)
    float v0 = 0.f, v1 = 0.f;
    for (int it = 0; it < 5; it++) {
      // v = W u  (rows lane, lane+64; per-lane contiguous float4 row stream)
      float a0 = 0.f, a1 = 0.f;
      #pragma unroll
      for (int k4 = 0; k4 < 16; k4++) {                     // k = 0..63
        float4 w0 = r0[k4], w1 = r1[k4];
        float uk;
        uk = __shfl(u0, 4*k4+0); a0 += w0.x*uk; a1 += w1.x*uk;
        uk = __shfl(u0, 4*k4+1); a0 += w0.y*uk; a1 += w1.y*uk;
        uk = __shfl(u0, 4*k4+2); a0 += w0.z*uk; a1 += w1.z*uk;
        uk = __shfl(u0, 4*k4+3); a0 += w0.w*uk; a1 += w1.w*uk;
      }
      #pragma unroll
      for (int k4 = 16; k4 < 32; k4++) {                    // k = 64..127
        float4 w0 = r0[k4], w1 = r1[k4];
        float uk;
        uk = __shfl(u1, 4*k4+0-64); a0 += w0.x*uk; a1 += w1.x*uk;
        uk = __shfl(u1, 4*k4+1-64); a0 += w0.y*uk; a1 += w1.y*uk;
        uk = __shfl(u1, 4*k4+2-64); a0 += w0.z*uk; a1 += w1.z*uk;
        uk = __shfl(u1, 4*k4+3-64); a0 += w0.w*uk; a1 += w1.w*uk;
      }
      float t = a0*a0 + a1*a1;
      #pragma unroll
      for (int off = 32; off > 0; off >>= 1) t += __shfl_xor(t, off);
      float nv = sqrtf(t) + 1e-12f;
      v0 = a0/nv; v1 = a1/nv;
      // u = W^T v  (coalesced: fixed row r, lanes read consecutive cols)
      float b0 = 0.f, b1 = 0.f;
      for (int r = 0; r < 64; r++) {
        float vr = __shfl(v0, r);
        b0 += W[r*FF+lane]*vr; b1 += W[r*FF+64+lane]*vr;
      }
      for (int r = 0; r < 64; r++) {
        float vr = __shfl(v1, r);
        b0 += W[(r+64)*FF+lane]*vr; b1 += W[(r+64)*FF+64+lane]*vr;
      }
      float t2 = b0*b0 + b1*b1;
      #pragma unroll
      for (int off = 32; off > 0; off >>= 1) t2 += __shfl_xor(t2, off);
      float nu = sqrtf(t2) + 1e-12f;
      u0 = b0/nu; u1 = b1/nu;
    }
    // sigma = v . (W u)
    float a0 = 0.f, a1 = 0.f;
    #pragma unroll
    for (int k4 = 0; k4 < 16; k4++) {
      float4 w0 = r0[k4], w1 = r1[k4];
      float uk;
      uk = __shfl(u0, 4*k4+0); a0 += w0.x*uk; a1 += w1.x*uk;
      uk = __shfl(u0, 4*k4+1); a0 += w0.y*uk; a1 += w1.y*uk;
      uk = __shfl(u0, 4*k4+2); a0 += w0.z*uk; a1 += w1.z*uk;
      uk = __shfl(u0, 4*k4+3); a0 += w0.w*uk; a1 += w1.w*uk;
    }
    #pragma unroll
    for (int k4 = 16; k4 < 32; k4++) {
      float4 w0 = r0[k4], w1 = r1[k4];
      float uk;
      uk = __shfl(u1, 4*k4+0-64); a0 += w0.x*uk; a1 += w1.x*uk;
      uk = __shfl(u1, 4*k4+1-64); a0 += w0.y*uk; a1 += w1.y*uk;
      uk = __shfl(u1, 4*k4+2-64); a0 += w0.z*uk; a1 += w1.z*uk;
      uk = __shfl(u1, 4*k4+3-64); a0 += w0.w*uk; a1 += w1.w*uk;
    }
    float dot = v0*a0 + v1*a1;
    #pragma unroll
    for (int off = 32; off > 0; off >>= 1) dot += __shfl_xor(dot, off);
    if (lane == 0) s_sigma[l] = dot;
  }
  __syncthreads();                                 // B2

  // ================= 3 conv layers, fully LDS-resident =================
  const float step  = 6.0f/127.0f;
  const float coeff = -0.5f/(step*step);
  for (int l = 0; l < 3; l++) {
    const float* Wfl = conv_Wf + l*3*FF*FF;
    const float* Wsl = conv_Ws + l*3*FF*FF;
    // ---- proj: group g -> mat w=g&3, atoms (g>>2)*12 .. +12, 12-way register block ----
    {
      const int w = g & 3;
      const int abase = (g >> 2) * 12;
      const float* Wm = (w==0) ? Wfl : (w==1) ? (Wfl+FF*FF) : (w==2) ? Wsl : (Wsl+FF*FF);
      float acc[12];
      #pragma unroll
      for (int t = 0; t < 12; t++) acc[t] = 0.f;
      const int q4 = abase >> 2;                   // 0 or 3
      for (int k = 0; k < FF; k++) {
        float wvv = Wm[k*FF+f];                    // coalesced row read, once per k
        const float4* r4 = (const float4*)(&s_ftT[k*28]);  // 112B rows: 16B-aligned
        float4 x0 = r4[q4+0], x1 = r4[q4+1], x2 = r4[q4+2]; // broadcast reads
        acc[0] += x0.x*wvv; acc[1] += x0.y*wvv; acc[2]  += x0.z*wvv; acc[3]  += x0.w*wvv;
        acc[4] += x1.x*wvv; acc[5] += x1.y*wvv; acc[6]  += x1.z*wvv; acc[7]  += x1.w*wvv;
        acc[8] += x2.x*wvv; acc[9] += x2.y*wvv; acc[10] += x2.z*wvv; acc[11] += x2.w*wvv;
      }
      #pragma unroll
      for (int t = 0; t < 12; t++) s_proj[((abase+t)*4+w)*FF+f] = acc[t];
    }
    __syncthreads();
    // ---- edges: group g owns atoms 3g..3g+2; in-place feat update ----
    {
      const float bff = conv_bf[l*FF+f];
      const float bsf = conv_bs[l*FF+f];
      const float* Wf2 = Wfl + 2*FF*FF;
      const float* Ws2 = Wsl + 2*FF*FF;
      for (int aa = 0; aa < 3; aa++) {
        const int a = g*3 + aa;
        const float gi = s_proj[(a*4+0)*FF+f];
        const float si = s_proj[(a*4+2)*FF+f];
        int n = s_cnt[a]; if (n > MAXNBR) n = MAXNBR;
        float msg = 0.f;
        for (int e = 0; e < n; e++) {
          const int   j    = s_nj[a*MAXNBR+e];
          const float dist = s_nd[a*MAXNBR+e];
          const float ww   = s_nw[a*MAXNBR+e];
          const float gj = s_proj[(j*4+1)*FF+f];
          const float sj = s_proj[(j*4+3)*FF+f];
          // banded Gaussian: |dist-k*step|>9*step terms < 2e-18 (exact fp32; validated R4-R7)
          float center = dist / step;
          int kmin = (int)ceilf(center - 9.0f);  if (kmin < 0)   kmin = 0;
          int kmax = (int)floorf(center + 9.0f); if (kmax > 127) kmax = 127;
          float ge = 0.f, se = 0.f;
          for (int k = kmin; k <= kmax; k++) {
            float dd = dist - step*(float)k;
            float av = expf(coeff*dd*dd);
            ge += av * Wf2[k*FF+f];
            se += av * Ws2[k*FF+f];
          }
          msg += sigmoidf(gi + gj + ge + bff) * softplusf(si + sj + se + bsf) * ww;
        }
        float fv = softplusf(s_ft[a*FF+f] + msg);
        s_ft[a*FF+f] = fv;     // safe: atom owned by this group only
        s_ftT[f*28+a] = fv;    // next layer's proj reads after barrier
      }
    }
    __syncthreads();
  }

  // ================= mean + spectral-normed FC chain + head =================
  if (tid < FF) {
    float s0 = 0.f;
    for (int a = 0; a < NN; a++) s0 += s_ft[a*FF+tid];
    s_hh[tid] = s0/(float)NN;
  }
  __syncthreads();
  for (int l = 0; l < 3; l++) {
    {   // 8-way k-split matvec across all 1024 threads
      float p = 0.f;
      #pragma unroll
      for (int k = g*16; k < g*16+16; k++) p += s_hh[k]*fc_W[l*FF*FF + k*FF + f];
      s_part[g][f] = p;
    }
    __syncthreads();
    if (tid < FF) {
      float s = 0.f;
      #pragma unroll
      for (int q = 0; q < 8; q++) s += s_part[q][tid];
      s_tmp[tid] = softplusf(s/s_sigma[l] + fc_b[l*FF+tid]);
    }
    __syncthreads();
    if (tid < FF) s_hh[tid] = s_tmp[tid];
    __syncthreads();
  }
  if (tid < FF) s_red[tid] = s_hh[tid]*W_out[tid];
  __syncthreads();
  if (tid < 64) {
    float t = s_red[tid] + s_red[tid+64];
    #pragma unroll
    for (int off = 32; off > 0; off >>= 1) t += __shfl_xor(t, off);
    if (tid == 0) out[b] = t + b_out[0];
  }
}

extern "C" void kernel_launch(void* const* d_in, const int* in_sizes, int n_in,
                              void* d_out, int out_size, void* d_ws, size_t ws_size,
                              hipStream_t stream) {
  const float* pos     = (const float*)d_in[0];
  const float* cell    = (const float*)d_in[1];
  const float* emb     = (const float*)d_in[2];
  const float* conv_Wf = (const float*)d_in[3];
  const float* conv_bf = (const float*)d_in[4];
  const float* conv_Ws = (const float*)d_in[5];
  const float* conv_bs = (const float*)d_in[6];
  const float* fc_W    = (const float*)d_in[7];
  const float* fc_b    = (const float*)d_in[8];
  const float* W_out   = (const float*)d_in[9];
  const float* b_out   = (const float*)d_in[10];
  const int*   z       = (const int*)d_in[11];
  // d_in[12] = batch (unused); d_ws unused. All tensors fp32 (validated R3-R7).

  k_fused<<<NB, 1024, 0, stream>>>(pos, cell, emb,
                                   conv_Wf, conv_bf, conv_Ws, conv_bs,
                                   fc_W, fc_b, W_out, b_out, z, (float*)d_out);
}

// Round 9
// 239.194 us; speedup vs baseline: 1.8065x; 1.8065x over previous
//
#include <hip/hip_runtime.h>
#include <math.h>

#define NB 16
#define NN 24
#define NA 384        /* atoms total */
#define FF 128
#define CC 27
#define MAXNBR 32     /* physically <= 23 possible (image spacing L > 2r) */
#define NCAND (NN*CC) /* 648 candidates per atom */

// ---- static device scratch. g_flag/g_arrive are reset to 0 by the final blocks of every
// call (arrive==24 guarantees no further readers), so each call starts from a clean state.
// ALL cross-block data goes through agent-scope relaxed atomics (sc0/sc1 LLC-coherent ops,
// no cache-wide flushes).
__device__ int   g_flag[NA];        // 0=start, 1=P0 done, 2=E0+P1, 3=E1+P2
__device__ int   g_arrive[NB];      // per-batch arrival counter (E2 completions)
__device__ float g_projA[NA*4*FF];  // layers 0,2
__device__ float g_projB[NA*4*FF];  // layer 1
__device__ float g_feat[NA*FF];     // final feats for the FC head

__device__ __forceinline__ float softplusf(float x){ return fmaxf(x,0.f) + log1pf(expf(-fabsf(x))); }
__device__ __forceinline__ float sigmoidf(float x){ return 1.f/(1.f+expf(-x)); }

__device__ __forceinline__ void st_agent(float* p, float v){
  __hip_atomic_store(p, v, __ATOMIC_RELAXED, __HIP_MEMORY_SCOPE_AGENT);
}
__device__ __forceinline__ float ld_agent(const float* p){
  return __hip_atomic_load(p, __ATOMIC_RELAXED, __HIP_MEMORY_SCOPE_AGENT);
}
__device__ __forceinline__ void st_agent_i(int* p, int v){
  __hip_atomic_store(p, v, __ATOMIC_RELAXED, __HIP_MEMORY_SCOPE_AGENT);
}
__device__ __forceinline__ int ld_agent_i(const int* p){
  return __hip_atomic_load(p, __ATOMIC_RELAXED, __HIP_MEMORY_SCOPE_AGENT);
}

// blocks 0..NA-1: one atom each (feat0, nbr list, P0, 3 conv layers, flag hand-off)
// blocks NA..NA+NB-1: one batch each (sigma via wave-shuffle, poll arrivals, mean+FC+head, reset)
__global__ void __launch_bounds__(512, 4)
k_all(const float* __restrict__ pos,  const float* __restrict__ cell,
      const float* __restrict__ emb,
      const float* __restrict__ conv_Wf, const float* __restrict__ conv_bf,
      const float* __restrict__ conv_Ws, const float* __restrict__ conv_bs,
      const float* __restrict__ fc_W,  const float* __restrict__ fc_b,
      const float* __restrict__ W_out, const float* __restrict__ b_out,
      const int* __restrict__ z,       float* __restrict__ out)
{
  const int bid = blockIdx.x, tid = threadIdx.x;
  const int g = tid >> 7, f = tid & 127;      // 4 groups x 128 lanes

  __shared__ float s_cell[9];
  __shared__ float s_pos[NN*3];
  __shared__ float s_ft[FF];
  __shared__ float s_gi[FF], s_si[FF];
  __shared__ int   s_nj[MAXNBR];
  __shared__ float s_nd[MAXNBR], s_nw[MAXNBR];
  __shared__ int   s_cnt;
  __shared__ float s_msg[4][FF];
  __shared__ float s_sigma[3];
  __shared__ float s_hh[FF], s_tmp[FF], s_part[4][FF], s_red[FF];

  if (bid < NA) {
    // ======================= atom block =======================
    const int i  = bid;
    const int b  = i / NN;
    const int il = i - b*NN;
    if (tid < 9)    s_cell[tid] = cell[b*9+tid];
    if (tid < NN*3) s_pos[tid]  = pos[b*NN*3+tid];
    if (tid == 0)   s_cnt = 0;
    if (tid < FF) {
      int zi = z[i]; if (zi < 1) zi = 1; if (zi > 100) zi = 100;
      s_ft[tid] = tanhf(emb[(zi-1)*FF+tid]);
    }
    __syncthreads();
    float cx = s_cell[4]*s_cell[8]-s_cell[5]*s_cell[7];
    float cy = s_cell[5]*s_cell[6]-s_cell[3]*s_cell[8];
    float cz = s_cell[3]*s_cell[7]-s_cell[4]*s_cell[6];
    float vol = s_cell[0]*cx+s_cell[1]*cy+s_cell[2]*cz;
    const float rb  = cbrtf(fabsf(vol)/(float)NN);   // RADIUS_RATE = 1
    const float rb2 = rb*rb;
    const float pix=s_pos[il*3+0], piy=s_pos[il*3+1], piz=s_pos[il*3+2];
    const float PI = 3.14159265358979323846f;
    for (int cand = tid; cand < NCAND; cand += 512) {
      int j = cand / CC, c = cand - j*CC;
      float gx = (float)(c/9) - 1.0f;
      float gy = (float)((c/3)%3) - 1.0f;
      float gz = (float)(c%3) - 1.0f;
      float ox = gx*s_cell[0] + gy*s_cell[3] + gz*s_cell[6];
      float oy = gx*s_cell[1] + gy*s_cell[4] + gz*s_cell[7];
      float oz = gx*s_cell[2] + gy*s_cell[5] + gz*s_cell[8];
      float dx = pix - (s_pos[j*3+0] + ox);
      float dy = piy - (s_pos[j*3+1] + oy);
      float dz = piz - (s_pos[j*3+2] + oz);
      float d2 = dx*dx + dy*dy + dz*dz;
      if (d2 <= rb2 && d2 > 1e-4f) {
        float dist = sqrtf(fmaxf(d2, 1e-12f));
        float w = cosf(dist*PI/rb) + 1.0f;
        int slot = atomicAdd(&s_cnt, 1);
        if (slot < MAXNBR) { s_nj[slot]=b*NN+j; s_nd[slot]=dist; s_nw[slot]=w; }
      }
    }
    __syncthreads();
    int n = s_cnt; if (n > MAXNBR) n = MAXNBR;

    // ---- P0 (group g -> one of gi,gj,si,sj) ----
    {
      const float* W = (g==0)?conv_Wf:(g==1)?(conv_Wf+FF*FF):(g==2)?conv_Ws:(conv_Ws+FF*FF);
      float s = 0.f;
      #pragma unroll 8
      for (int k=0;k<FF;k++) s += s_ft[k]*W[k*FF+f];
      if (g==0) s_gi[f]=s;
      if (g==2) s_si[f]=s;
      st_agent(&g_projA[(i*4+g)*FF+f], s);
    }
    asm volatile("s_waitcnt vmcnt(0)" ::: "memory");
    __syncthreads();                                   // all proj stores acked (LLC)
    if (tid == 0) st_agent_i(&g_flag[i], 1);

    const float step  = 6.0f/127.0f;
    const float coeff = -0.5f/(step*step);
    for (int l = 0; l < 3; l++) {
      const float* projSrc = (l==1) ? g_projB : g_projA;
      float*       projDst = (l==1) ? g_projA : g_projB;
      if (tid == 0) {
        for (int e = 0; e < n; e++) {
          int jg = s_nj[e];
          while (ld_agent_i(&g_flag[jg]) < l+1) __builtin_amdgcn_s_sleep(2);
        }
      }
      __syncthreads();                                 // flag observed -> proj valid at LLC
      const float gi = s_gi[f], si = s_si[f];
      const float bff = conv_bf[l*FF+f], bsf = conv_bs[l*FF+f];
      const float* Wf2 = conv_Wf + l*3*FF*FF + 2*FF*FF;
      const float* Ws2 = conv_Ws + l*3*FF*FF + 2*FF*FF;
      float msg = 0.f;
      for (int e = g; e < n; e += 4) {
        const int   jg   = s_nj[e];
        const float dist = s_nd[e];
        const float ww   = s_nw[e];
        const float gj = ld_agent(&projSrc[(jg*4+1)*FF+f]);  // sc1: LLC-coherent
        const float sj = ld_agent(&projSrc[(jg*4+3)*FF+f]);
        // banded Gaussian: |dist-k*step|>9*step terms < 2e-18 (exact fp32; validated R4-R8)
        float center = dist / step;
        int kmin = (int)ceilf(center - 9.0f);  if (kmin < 0)   kmin = 0;
        int kmax = (int)floorf(center + 9.0f); if (kmax > 127) kmax = 127;
        float ge = 0.f, se = 0.f;
        for (int k = kmin; k <= kmax; k++) {
          float dd = dist - step*(float)k;
          float av = expf(coeff*dd*dd);
          ge += av * Wf2[k*FF+f];
          se += av * Ws2[k*FF+f];
        }
        msg += sigmoidf(gi + gj + ge + bff) * softplusf(si + sj + se + bsf) * ww;
      }
      s_msg[g][f] = msg;
      __syncthreads();
      if (tid < FF)
        s_ft[f] = softplusf(s_ft[f] + s_msg[0][f]+s_msg[1][f]+s_msg[2][f]+s_msg[3][f]);
      __syncthreads();
      if (l < 2) {
        const float* WfN = conv_Wf + (l+1)*3*FF*FF;
        const float* WsN = conv_Ws + (l+1)*3*FF*FF;
        const float* W = (g==0)?WfN:(g==1)?(WfN+FF*FF):(g==2)?WsN:(WsN+FF*FF);
        float s = 0.f;
        #pragma unroll 8
        for (int k=0;k<FF;k++) s += s_ft[k]*W[k*FF+f];
        if (g==0) s_gi[f]=s;
        if (g==2) s_si[f]=s;
        st_agent(&projDst[(i*4+g)*FF+f], s);
        asm volatile("s_waitcnt vmcnt(0)" ::: "memory");
        __syncthreads();
        if (tid == 0) st_agent_i(&g_flag[i], l+2);
      } else {
        if (tid < FF) st_agent(&g_feat[i*FF+f], s_ft[f]);
        asm volatile("s_waitcnt vmcnt(0)" ::: "memory");
        __syncthreads();
        if (tid == 0) atomicAdd(&g_arrive[b], 1);      // device-scope RMW (LLC)
      }
    }
  } else {
    // ======================= batch block: sigma + final =======================
    const int b2 = bid - NA;
    const int wv = tid >> 6, lane = tid & 63;
    if (wv < 3) {
      // wave-synchronous power iteration (validated R8: absmax 0.0)
      const int l = wv;
      const float* W = fc_W + l*FF*FF;
      const float4* r0 = (const float4*)(W + lane*FF);
      const float4* r1 = (const float4*)(W + (lane+64)*FF);
      float u0 = 0.08838834764831845f, u1 = u0;        // ones/||ones|| = 1/sqrt(128)
      float v0 = 0.f, v1 = 0.f;
      for (int it = 0; it < 5; it++) {
        float a0 = 0.f, a1 = 0.f;
        #pragma unroll
        for (int k4 = 0; k4 < 16; k4++) {
          float4 w0 = r0[k4], w1 = r1[k4]; float uk;
          uk = __shfl(u0, 4*k4+0); a0 += w0.x*uk; a1 += w1.x*uk;
          uk = __shfl(u0, 4*k4+1); a0 += w0.y*uk; a1 += w1.y*uk;
          uk = __shfl(u0, 4*k4+2); a0 += w0.z*uk; a1 += w1.z*uk;
          uk = __shfl(u0, 4*k4+3); a0 += w0.w*uk; a1 += w1.w*uk;
        }
        #pragma unroll
        for (int k4 = 16; k4 < 32; k4++) {
          float4 w0 = r0[k4], w1 = r1[k4]; float uk;
          uk = __shfl(u1, 4*k4+0-64); a0 += w0.x*uk; a1 += w1.x*uk;
          uk = __shfl(u1, 4*k4+1-64); a0 += w0.y*uk; a1 += w1.y*uk;
          uk = __shfl(u1, 4*k4+2-64); a0 += w0.z*uk; a1 += w1.z*uk;
          uk = __shfl(u1, 4*k4+3-64); a0 += w0.w*uk; a1 += w1.w*uk;
        }
        float t = a0*a0 + a1*a1;
        #pragma unroll
        for (int off = 32; off > 0; off >>= 1) t += __shfl_xor(t, off);
        float nv = sqrtf(t) + 1e-12f;
        v0 = a0/nv; v1 = a1/nv;
        float b0 = 0.f, b1 = 0.f;
        for (int r = 0; r < 64; r++) {
          float vr = __shfl(v0, r);
          b0 += W[r*FF+lane]*vr; b1 += W[r*FF+64+lane]*vr;
        }
        for (int r = 0; r < 64; r++) {
          float vr = __shfl(v1, r);
          b0 += W[(r+64)*FF+lane]*vr; b1 += W[(r+64)*FF+64+lane]*vr;
        }
        float t2 = b0*b0 + b1*b1;
        #pragma unroll
        for (int off = 32; off > 0; off >>= 1) t2 += __shfl_xor(t2, off);
        float nu = sqrtf(t2) + 1e-12f;
        u0 = b0/nu; u1 = b1/nu;
      }
      float a0 = 0.f, a1 = 0.f;
      #pragma unroll
      for (int k4 = 0; k4 < 16; k4++) {
        float4 w0 = r0[k4], w1 = r1[k4]; float uk;
        uk = __shfl(u0, 4*k4+0); a0 += w0.x*uk; a1 += w1.x*uk;
        uk = __shfl(u0, 4*k4+1); a0 += w0.y*uk; a1 += w1.y*uk;
        uk = __shfl(u0, 4*k4+2); a0 += w0.z*uk; a1 += w1.z*uk;
        uk = __shfl(u0, 4*k4+3); a0 += w0.w*uk; a1 += w1.w*uk;
      }
      #pragma unroll
      for (int k4 = 16; k4 < 32; k4++) {
        float4 w0 = r0[k4], w1 = r1[k4]; float uk;
        uk = __shfl(u1, 4*k4+0-64); a0 += w0.x*uk; a1 += w1.x*uk;
        uk = __shfl(u1, 4*k4+1-64); a0 += w0.y*uk; a1 += w1.y*uk;
        uk = __shfl(u1, 4*k4+2-64); a0 += w0.z*uk; a1 += w1.z*uk;
        uk = __shfl(u1, 4*k4+3-64); a0 += w0.w*uk; a1 += w1.w*uk;
      }
      float dot = v0*a0 + v1*a1;
      #pragma unroll
      for (int off = 32; off > 0; off >>= 1) dot += __shfl_xor(dot, off);
      if (lane == 0) s_sigma[l] = dot;
    }
    // all threads wait for this batch's 24 atoms
    while (ld_agent_i(&g_arrive[b2]) < NN) __builtin_amdgcn_s_sleep(8);
    __syncthreads();
    if (tid < FF) {
      float s0 = 0.f;
      for (int a = 0; a < NN; a++) s0 += ld_agent(&g_feat[(b2*NN+a)*FF+tid]);
      s_hh[tid] = s0/(float)NN;
    }
    __syncthreads();
    for (int l = 0; l < 3; l++) {
      { float p = 0.f;
        #pragma unroll
        for (int k = g*32; k < g*32+32; k++) p += s_hh[k]*fc_W[l*FF*FF + k*FF + f];
        s_part[g][f] = p; }
      __syncthreads();
      if (tid < FF) {
        float s = s_part[0][tid]+s_part[1][tid]+s_part[2][tid]+s_part[3][tid];
        s_tmp[tid] = softplusf(s/s_sigma[l] + fc_b[l*FF+tid]);
      }
      __syncthreads();
      if (tid < FF) s_hh[tid] = s_tmp[tid];
      __syncthreads();
    }
    if (tid < FF) s_red[tid] = s_hh[tid]*W_out[tid];
    __syncthreads();
    if (tid < 64) {
      float t = s_red[tid] + s_red[tid+64];
      #pragma unroll
      for (int off = 32; off > 0; off >>= 1) t += __shfl_xor(t, off);
      if (tid == 0) out[b2] = t + b_out[0];
    }
    // reset sync state for the next call (no further readers: arrive==24 observed)
    __syncthreads();
    if (tid < NN) st_agent_i(&g_flag[b2*NN+tid], 0);
    if (tid == 0) st_agent_i(&g_arrive[b2], 0);
  }
}

extern "C" void kernel_launch(void* const* d_in, const int* in_sizes, int n_in,
                              void* d_out, int out_size, void* d_ws, size_t ws_size,
                              hipStream_t stream) {
  const float* pos     = (const float*)d_in[0];
  const float* cell    = (const float*)d_in[1];
  const float* emb     = (const float*)d_in[2];
  const float* conv_Wf = (const float*)d_in[3];
  const float* conv_bf = (const float*)d_in[4];
  const float* conv_Ws = (const float*)d_in[5];
  const float* conv_bs = (const float*)d_in[6];
  const float* fc_W    = (const float*)d_in[7];
  const float* fc_b    = (const float*)d_in[8];
  const float* W_out   = (const float*)d_in[9];
  const float* b_out   = (const float*)d_in[10];
  const int*   z       = (const int*)d_in[11];
  // d_in[12] = batch (unused); d_ws unused. All tensors fp32 (validated R3-R8).

  k_all<<<NA+NB, 512, 0, stream>>>(pos, cell, emb,
                                   conv_Wf, conv_bf, conv_Ws, conv_bs,
                                   fc_W, fc_b, W_out, b_out, z, (float*)d_out);
}